// Round 2
// baseline (130.920 us; speedup 1.0000x reference)
//
#include <hip/hip_runtime.h>
#include <math.h>

// Problem constants (reference: N=256, S=1, stimulus 144x256, retina 144x256)
#define NB    256
#define IMG_H 144
#define IMG_W 256
#define IMG_ELEMS (IMG_H * IMG_W)   // 36864 floats
#define HR    144
#define WR    256
#define FDIM  16
#define DDIM  128

#define FOV_HALF_RAD 0.6544984694978736f   // 0.5 * 75deg in rad
#define GELU_GAMMA   1.7015043497085571f
#define OUT_OF_RANGE 10.0f

// gather kernel geometry: 256 threads (one output column per lane),
// 8 rows per block -> 2048 px/block, 18 blocks/image, 4608 blocks total
#define BLOCKS_PER_IMG 18
#define K2_BLOCKS (NB * BLOCKS_PER_IMG)   // 4608, divisible by 8 XCDs

typedef float f32x4 __attribute__((ext_vector_type(4)));

// jax.nn.gelu default is approximate=True (tanh form)
__device__ __forceinline__ float gelu_gamma(float x) {
    const float k0 = 0.7978845608028654f;  // sqrt(2/pi)
    const float k1 = 0.044715f;
    float t = tanhf(k0 * (x + k1 * x * x * x));
    return 0.5f * x * (1.0f + t) * GELU_GAMMA;
}

// One block per batch element; 128 threads = hidden dim. Writes R into d_ws
// (the harness poisons d_ws unconditionally -- measured identical 256 MiB
// fills whether or not d_ws is used -- so the workspace is free).
__global__ void __launch_bounds__(DDIM) mlp_rmat_kernel(
    const float* __restrict__ persp,  // [NB, FDIM]
    const float* __restrict__ W1,     // [FDIM, DDIM]
    const float* __restrict__ b1,     // [DDIM]
    const float* __restrict__ W2,     // [DDIM, DDIM]
    const float* __restrict__ b2,     // [DDIM]
    const float* __restrict__ Wp,     // [DDIM, 3]
    const float* __restrict__ bp,     // [3]
    float* __restrict__ Rout)         // [NB, 9]
{
    const int n = blockIdx.x;
    const int d = threadIdx.x;

    __shared__ float sh1[DDIM];
    __shared__ float sh2[DDIM];
    __shared__ float ang[3];

    float acc = b1[d];
#pragma unroll
    for (int f = 0; f < FDIM; ++f)
        acc = fmaf(persp[n * FDIM + f], W1[f * DDIM + d], acc);
    sh1[d] = gelu_gamma(acc);
    __syncthreads();

    float acc2 = b2[d];
#pragma unroll 8
    for (int k = 0; k < DDIM; ++k)
        acc2 = fmaf(sh1[k], W2[k * DDIM + d], acc2);
    sh2[d] = gelu_gamma(acc2);
    __syncthreads();

    if (d < 3) {
        float a = bp[d];
#pragma unroll 8
        for (int k = 0; k < DDIM; ++k)
            a = fmaf(sh2[k], Wp[k * 3 + d], a);
        ang[d] = a;
    }
    __syncthreads();

    if (d == 0) {
        float cx = cosf(ang[0]), sx = sinf(ang[0]);
        float cy = cosf(ang[1]), sy = sinf(ang[1]);
        float cz = cosf(ang[2]), sz = sinf(ang[2]);
        float* R = Rout + n * 9;
        R[0] = cz * cy;  R[1] = cz * sy * sx - sz * cx;  R[2] = cz * sy * cx + sz * sx;
        R[3] = sz * cy;  R[4] = sz * sy * sx + cz * cx;  R[5] = sz * sy * cx - cz * sx;
        R[6] = -sy;      R[7] = cy * sx;                 R[8] = cy * cx;
    }
}

// Gather straight from global memory (no LDS staging, no barrier, no
// occupancy cliff). The bilinear footprint of a wave is ~85 consecutive
// floats across 1-2 rows -> loads coalesce into a few 64B lines and hit
// L1/L2. Bijective XCD swizzle keeps each XCD's L2 on a contiguous chunk
// of 32 images (~4.6 MiB, streaming).
__global__ void __launch_bounds__(256, 4) retina_gather_kernel(
    const float* __restrict__ stim,   // [NB, 1, IMG_H, IMG_W]
    const float* __restrict__ Rmat,   // [NB, 9]
    float* __restrict__ out)          // [NB, 1, HR, WR]
{
    // XCD-aware swizzle: hw round-robins blockIdx across 8 XCDs; remap so
    // each XCD owns a contiguous chunk of the grid (4608 % 8 == 0 -> bijective)
    const int per = K2_BLOCKS / 8;                    // 576
    const int bid = blockIdx.x;
    const int wg  = (bid & 7) * per + (bid >> 3);

    const int n   = wg / BLOCKS_PER_IMG;
    const int blk = wg - n * BLOCKS_PER_IMG;
    const int h0  = blk * 8;                          // first output row
    const int w   = threadIdx.x;                      // output column (0..255)

    // block-uniform rotation matrix -> scalar loads
    const float* __restrict__ Rn = Rmat + n * 9;
    const float r0 = Rn[0], r1 = Rn[1], r2 = Rn[2];
    const float r3 = Rn[3], r4 = Rn[4], r5 = Rn[5];
    const float r6 = Rn[6], r7 = Rn[7], r8 = Rn[8];

    const float* __restrict__ img  = stim + (size_t)n * IMG_ELEMS;
    float* __restrict__ outn = out + (size_t)n * IMG_ELEMS + (size_t)h0 * IMG_W;

    // per-thread (column) constants
    const float gx  = ((float)(2 * w + 1) - 256.0f) * (1.0f / 256.0f);
    const float axv = gx * FOV_HALF_RAD;
    const float ax2 = axv * axv;

#pragma unroll 4
    for (int i = 0; i < 8; ++i) {
        const int h = h0 + i;
        const float gy  = ((float)(2 * h + 1) - 144.0f) * (1.0f / 256.0f);
        const float ayv = gy * FOV_HALF_RAD;
        const float tt  = fmaf(ayv, ayv, ax2);        // a^2 <= 0.56

        // sinc(a): even Taylor in t, |err| ~1e-8 on this range
        float sc = fmaf(tt, 2.7557319e-6f, -1.9841270e-4f);
        sc = fmaf(tt, sc,  8.3333333e-3f);
        sc = fmaf(tt, sc, -1.6666667e-1f);
        sc = fmaf(tt, sc,  1.0f);

        // cos(a): even Taylor in t
        float ca = fmaf(tt, 2.4801587e-5f, -1.3888889e-3f);
        ca = fmaf(tt, ca,  4.1666667e-2f);
        ca = fmaf(tt, ca, -0.5f);
        ca = fmaf(tt, ca,  1.0f);

        const float dx = sc * axv, dy = sc * ayv, dz = ca;

        const float rx = fmaf(r0, dx, fmaf(r1, dy, r2 * dz));
        const float ry = fmaf(r3, dx, fmaf(r4, dy, r5 * dz));
        const float rz = fmaf(r6, dx, fmaf(r7, dy, r8 * dz));

        const float inv  = __builtin_amdgcn_rcpf(rz);
        const bool  safe = rz > 0.001f;
        const float gxp  = safe ? rx * inv : OUT_OF_RANGE;
        const float gyp  = safe ? ry * inv : OUT_OF_RANGE;

        const float pxf = fmaf(gxp, 256.0f, (float)(IMG_W - 1)) * 0.5f;
        const float pyf = fmaf(gyp, 256.0f, (float)(IMG_H - 1)) * 0.5f;

        const float x0f = floorf(pxf), y0f = floorf(pyf);
        const float wx  = pxf - x0f,   wy  = pyf - y0f;
        const int   x0  = (int)x0f,    y0  = (int)y0f;
        const int   x1  = x0 + 1,      y1  = y0 + 1;

        // validity per corner (reference: constant zero padding)
        const bool vx0 = (unsigned)x0 < IMG_W;
        const bool vx1 = (unsigned)x1 < IMG_W;
        const bool vy0 = (unsigned)y0 < IMG_H;
        const bool vy1 = (unsigned)y1 < IMG_H;

        // clamped addresses (always in-bounds loads; invalid values masked)
        const int xc0 = min(max(x0, 0), IMG_W - 1);
        const int xc1 = min(max(x1, 0), IMG_W - 1);
        const int yb0 = min(max(y0, 0), IMG_H - 1) << 8;   // *IMG_W
        const int yb1 = min(max(y1, 0), IMG_H - 1) << 8;

        const float l00 = img[yb0 + xc0];
        const float l01 = img[yb0 + xc1];
        const float l10 = img[yb1 + xc0];
        const float l11 = img[yb1 + xc1];

        const float c00 = (vx0 & vy0) ? l00 : 0.0f;
        const float c01 = (vx1 & vy0) ? l01 : 0.0f;
        const float c10 = (vx0 & vy1) ? l10 : 0.0f;
        const float c11 = (vx1 & vy1) ? l11 : 0.0f;

        const float top = fmaf(wx, c01 - c00, c00);
        const float bot = fmaf(wx, c11 - c10, c10);
        const float res = fmaf(wy, bot - top, top);

        __builtin_nontemporal_store(res, outn + i * IMG_W + w);
    }
}

extern "C" void kernel_launch(void* const* d_in, const int* in_sizes, int n_in,
                              void* d_out, int out_size, void* d_ws, size_t ws_size,
                              hipStream_t stream) {
    const float* stimulus    = (const float*)d_in[0]; // [256,1,144,256]
    const float* perspective = (const float*)d_in[1]; // [256,16]
    const float* W1          = (const float*)d_in[2]; // [16,128]
    const float* b1          = (const float*)d_in[3]; // [128]
    const float* W2          = (const float*)d_in[4]; // [128,128]
    const float* b2          = (const float*)d_in[5]; // [128]
    const float* Wp          = (const float*)d_in[6]; // [128,3]
    const float* bp          = (const float*)d_in[7]; // [3]
    float* out = (float*)d_out;

    float* Rmat = (float*)d_ws;   // 256*9 floats; d_ws poison happens regardless

    mlp_rmat_kernel<<<NB, DDIM, 0, stream>>>(
        perspective, W1, b1, W2, b2, Wp, bp, Rmat);

    retina_gather_kernel<<<K2_BLOCKS, 256, 0, stream>>>(stimulus, Rmat, out);
}

// Round 3
// 114.346 us; speedup vs baseline: 1.1449x; 1.1449x over previous
//
#include <hip/hip_runtime.h>
#include <math.h>

// Problem constants (reference: N=256, S=1, stimulus 144x256, retina 144x256)
#define NB    256
#define IMG_H 144
#define IMG_W 256
#define IMG_ELEMS (IMG_H * IMG_W)   // 36864 floats
#define HR    144
#define WR    256
#define FDIM  16
#define DDIM  128

// LDS image layout: zero-bordered.
//   stored row s = src_row + 1, s in [0,146]; row stride 260 floats (1040 B, 16B aligned)
//   data col c at offset c+4 (offsets 4..259); offset 3 = left zero border (x=-1)
//   offsets 260,261 of a row = offsets 0,1 of next row (right border x=256,257) -> zeroed
//   rows s=0 (y=-1), s=145 (y=144), s=146 (y=145) fully zero; tail group at 147*260
#define STRIDE 260
#define SIMG_FLOATS (147 * STRIDE + 4)   // 38224 floats = 149.3 KiB

#define FOV_HALF_RAD 0.6544984694978736f   // 0.5 * 75deg in rad
#define GELU_GAMMA   1.7015043497085571f
#define OUT_OF_RANGE 10.0f

typedef float f32x4 __attribute__((ext_vector_type(4)));
typedef const __attribute__((address_space(1))) unsigned int glb_u32;
typedef __attribute__((address_space(3))) unsigned int lds_u32;

// jax.nn.gelu default is approximate=True (tanh form)
__device__ __forceinline__ float gelu_gamma(float x) {
    const float k0 = 0.7978845608028654f;  // sqrt(2/pi)
    const float k1 = 0.044715f;
    float t = tanhf(k0 * (x + k1 * x * x * x));
    return 0.5f * x * (1.0f + t) * GELU_GAMMA;
}

// Fully fused: per-image MLP -> rotation matrix -> retina resample.
// One block per image, 1024 threads. Waves 1..15 stage the image into LDS via
// global_load_lds (one wave-issue = one image row, direct HBM->LDS, no VGPR
// round-trip); wave 0 runs the MLP concurrently. d_ws unused (harness poisons
// it unconditionally either way -- measured identical 2x256MiB fills).
__global__ void __launch_bounds__(1024, 4) fused_retina_kernel(
    const float* __restrict__ stim,   // [NB, 1, IMG_H, IMG_W]
    const float* __restrict__ persp,  // [NB, FDIM]
    const float* __restrict__ W1,     // [FDIM, DDIM]
    const float* __restrict__ b1,     // [DDIM]
    const float* __restrict__ W2,     // [DDIM, DDIM]
    const float* __restrict__ b2,     // [DDIM]
    const float* __restrict__ Wp,     // [DDIM, 3]
    const float* __restrict__ bp,     // [3]
    float* __restrict__ out)          // [NB, 1, HR, WR]
{
    __shared__ float simg[SIMG_FLOATS];
    __shared__ float sh1[DDIM];
    __shared__ float sh2[DDIM];
    __shared__ float sAng[3];
    __shared__ float sR[9];

    const int tid  = threadIdx.x;
    const int n    = blockIdx.x;
    const int wid  = tid >> 6;
    const int lane = tid & 63;

    const float* __restrict__ img = stim + (size_t)n * IMG_ELEMS;

    // ---- zero the border cells (340 f32x4 groups, disjoint from staged data)
    if (tid < 340) {
        f32x4 z = {0.0f, 0.0f, 0.0f, 0.0f};
        int idx;
        if (tid < 195) {                       // full zero rows s=0,145,146
            const int rr = tid / 65;
            const int g  = tid - rr * 65;      // 0..64 -> offsets 0..259
            const int s  = (rr == 0) ? 0 : (144 + rr);
            idx = s * STRIDE + g * 4;
        } else if (tid < 339) {                // left borders of data rows s=1..144
            idx = (tid - 194) * STRIDE;        // offsets 0..3
        } else {                               // tail cells after row s=146
            idx = 147 * STRIDE;                // 38220..38223
        }
        *(f32x4*)&simg[idx] = z;
    }

    if (wid > 0) {
        // ---- waves 1..15: async stage, one image row per wave-issue.
        // 64 lanes x 16B = 1024B = one 256-float row; LDS dest = uniform base
        // + lane*16 (hardware), global src = per-lane address.
        const int v = wid - 1;                 // 0..14
#pragma unroll
        for (int p = 0; p < 10; ++p) {
            const int r = v + 15 * p;
            if (r < IMG_H) {
                const float* gsrc = img + (size_t)r * IMG_W + lane * 4;
                float* ldst = &simg[(r + 1) * STRIDE + 4];
                __builtin_amdgcn_global_load_lds(
                    (glb_u32*)gsrc, (lds_u32*)ldst, 16, 0, 0);
            }
        }
    } else {
        // ---- wave 0: the whole MLP, single-wave (lgkmcnt orders LDS within wave)
        float a0 = b1[lane], a1 = b1[lane + 64];
#pragma unroll
        for (int f = 0; f < FDIM; ++f) {
            const float p = persp[n * FDIM + f];
            a0 = fmaf(p, W1[f * DDIM + lane],      a0);
            a1 = fmaf(p, W1[f * DDIM + lane + 64], a1);
        }
        sh1[lane]      = gelu_gamma(a0);
        sh1[lane + 64] = gelu_gamma(a1);
        asm volatile("s_waitcnt lgkmcnt(0)" ::: "memory");

        float c0 = b2[lane], c1 = b2[lane + 64];
#pragma unroll 8
        for (int k = 0; k < DDIM; ++k) {
            const float s = sh1[k];
            c0 = fmaf(s, W2[k * DDIM + lane],      c0);
            c1 = fmaf(s, W2[k * DDIM + lane + 64], c1);
        }
        sh2[lane]      = gelu_gamma(c0);
        sh2[lane + 64] = gelu_gamma(c1);
        asm volatile("s_waitcnt lgkmcnt(0)" ::: "memory");

        if (lane < 3) {
            float a = bp[lane];
#pragma unroll 8
            for (int k = 0; k < DDIM; ++k)
                a = fmaf(sh2[k], Wp[k * 3 + lane], a);
            sAng[lane] = a;
        }
        asm volatile("s_waitcnt lgkmcnt(0)" ::: "memory");

        if (lane == 0) {
            const float cx = cosf(sAng[0]), sx = sinf(sAng[0]);
            const float cy = cosf(sAng[1]), sy = sinf(sAng[1]);
            const float cz = cosf(sAng[2]), sz = sinf(sAng[2]);
            sR[0] = cz * cy;  sR[1] = cz * sy * sx - sz * cx;  sR[2] = cz * sy * cx + sz * sx;
            sR[3] = sz * cy;  sR[4] = sz * sy * sx + cz * cx;  sR[5] = sz * sy * cx - cz * sx;
            sR[6] = -sy;      sR[7] = cy * sx;                 sR[8] = cy * cx;
        }
    }
    __syncthreads();   // drains vmcnt (global_load_lds) + lgkmcnt for all waves

    // block-uniform rotation (LDS broadcast reads, conflict-free)
    const float r0 = sR[0], r1 = sR[1], r2 = sR[2];
    const float r3 = sR[3], r4 = sR[4], r5 = sR[5];
    const float r6 = sR[6], r7 = sR[7], r8 = sR[8];

    float* __restrict__ outn = out + (size_t)n * IMG_ELEMS;

    // ---- gather: lane-adjacent pixels (source lane-stride ~1 dword -> near
    // conflict-free ds_read); zero border removes all masks; column-constant
    // terms hoisted out of the loop.
    const int w     = tid & 255;           // output column: iteration-invariant
    const int hbase = tid >> 8;            // 0..3
    const float gx  = ((float)(2 * w + 1) - 256.0f) * (1.0f / 256.0f);
    const float axv = gx * FOV_HALF_RAD;
    const float ax2 = axv * axv;
    const float A0 = r0 * axv, A1 = r3 * axv, A2 = r6 * axv;

#pragma unroll 4
    for (int it = 0; it < 36; ++it) {
        const int h   = it * 4 + hbase;
        const int px0 = (h << 8) | w;

        const float gy  = ((float)(2 * h + 1) - 144.0f) * (1.0f / 256.0f);
        const float ayv = gy * FOV_HALF_RAD;
        const float tt  = fmaf(ayv, ayv, ax2);   // a^2 <= 0.56

        // sinc(a): even Taylor in t, |err| ~1e-8 on this range
        float sc = fmaf(tt, 2.7557319e-6f, -1.9841270e-4f);
        sc = fmaf(tt, sc,  8.3333333e-3f);
        sc = fmaf(tt, sc, -1.6666667e-1f);
        sc = fmaf(tt, sc,  1.0f);

        // cos(a): even Taylor in t
        float ca = fmaf(tt, 2.4801587e-5f, -1.3888889e-3f);
        ca = fmaf(tt, ca,  4.1666667e-2f);
        ca = fmaf(tt, ca, -0.5f);
        ca = fmaf(tt, ca,  1.0f);

        // rotated ray: r_i = sc*(R_i0*ax + R_i1*ay) + R_i2*ca
        const float rx = fmaf(sc, fmaf(r1, ayv, A0), r2 * ca);
        const float ry = fmaf(sc, fmaf(r4, ayv, A1), r5 * ca);
        const float rz = fmaf(sc, fmaf(r7, ayv, A2), r8 * ca);

        const float inv  = __builtin_amdgcn_rcpf(rz);
        const float s128 = 128.0f * inv;         // fold *256 and *0.5 into one scale
        const bool  safe = rz > 0.001f;

        float pxf = fmaf(rx, s128, 127.5f);
        float pyf = fmaf(ry, s128, 71.5f);
        pxf = safe ? pxf : 300.0f;               // out-of-range -> clamps to border
        pyf = safe ? pyf : 300.0f;
        // clamp onto the zero border: out-of-range lands on zero cells with
        // zero fractional weight -> exact per-corner mask semantics
        pxf = fminf(fmaxf(pxf, -1.0f), 256.0f);
        pyf = fminf(fmaxf(pyf, -1.0f), 144.0f);

        const float x0f = floorf(pxf), y0f = floorf(pyf);
        const float wx  = pxf - x0f,   wy  = pyf - y0f;
        const int   xi  = (int)x0f,    yi  = (int)y0f;   // xi in [-1,256], yi in [-1,144]

        const int a00 = yi * STRIDE + xi + (STRIDE + 4); // (yi+1)*STRIDE + xi + 4
        const int a10 = a00 + STRIDE;

        const float v00 = simg[a00];
        const float v01 = simg[a00 + 1];
        const float v10 = simg[a10];
        const float v11 = simg[a10 + 1];

        const float top = fmaf(wx, v01 - v00, v00);
        const float bot = fmaf(wx, v11 - v10, v10);
        const float res = fmaf(wy, bot - top, top);

        __builtin_nontemporal_store(res, outn + px0);
    }
}

extern "C" void kernel_launch(void* const* d_in, const int* in_sizes, int n_in,
                              void* d_out, int out_size, void* d_ws, size_t ws_size,
                              hipStream_t stream) {
    const float* stimulus    = (const float*)d_in[0]; // [256,1,144,256]
    const float* perspective = (const float*)d_in[1]; // [256,16]
    const float* W1          = (const float*)d_in[2]; // [16,128]
    const float* b1          = (const float*)d_in[3]; // [128]
    const float* W2          = (const float*)d_in[4]; // [128,128]
    const float* b2          = (const float*)d_in[5]; // [128]
    const float* Wp          = (const float*)d_in[6]; // [128,3]
    const float* bp          = (const float*)d_in[7]; // [3]
    float* out = (float*)d_out;

    (void)d_ws; (void)ws_size;

    fused_retina_kernel<<<NB, 1024, 0, stream>>>(
        stimulus, perspective, W1, b1, W2, b2, Wp, bp, out);
}